// Round 9
// baseline (6929.250 us; speedup 1.0000x reference)
//
#include <hip/hip_runtime.h>
#include <hip/hip_fp16.h>

#define N 8192
#define ITERS 50
#define ROWS 8     // rows per gemv block (fallback path)
#define RPB 16     // rows per block (persistent path)
#define NBLK 512   // persistent grid: 512 = 256 CU x 2 blocks/CU (co-resident)

typedef unsigned int uint32;

#define AS1 __attribute__((address_space(1)))
#define AS3 __attribute__((address_space(3)))

__device__ __forceinline__ void gload_lds16(const void* g, void* l) {
    __builtin_amdgcn_global_load_lds((const AS1 void*)g, (AS3 void*)l, 16, 0, 0);
}

__device__ __forceinline__ uint32 pack2h(float x, float y) {
    __half2 p = __float22half2_rn(make_float2(x, y));
    return *reinterpret_cast<uint32*>(&p);
}

__device__ __forceinline__ float2 h2f(uint32 u) {
    __half2 h = *reinterpret_cast<__half2*>(&u);
    return __half22float2(h);
}

// software grid barrier: one counter slot per barrier instance (zeroed per
// call by pi_init2_kernel). threadfence both sides for cross-XCD visibility.
__device__ __forceinline__ void gbar(int* cnt, int slot) {
    __syncthreads();
    __threadfence();
    if (threadIdx.x == 0) {
        __hip_atomic_fetch_add(&cnt[slot], 1, __ATOMIC_ACQ_REL,
                               __HIP_MEMORY_SCOPE_AGENT);
        while (__hip_atomic_load(&cnt[slot], __ATOMIC_ACQUIRE,
                                 __HIP_MEMORY_SCOPE_AGENT) < NBLK)
            __builtin_amdgcn_s_sleep(4);
    }
    __syncthreads();
    __threadfence();
}

// generic epilogue: per-row wave reduce -> LDS -> write vout rows, atomicAdd sum(y^2)
template <int R>
__device__ __forceinline__ void pi_epilogueT(float (&acc)[R], int t, int row0,
                                             float s, float* __restrict__ vout,
                                             float* __restrict__ nsq_next) {
#pragma unroll
    for (int r = 0; r < R; ++r) {
        float a = acc[r];
        for (int off = 32; off > 0; off >>= 1) a += __shfl_down(a, off, 64);
        acc[r] = a;
    }
    __shared__ float part[4][R];
    const int wave = t >> 6, lane = t & 63;
    if (lane == 0) {
#pragma unroll
        for (int r = 0; r < R; ++r) part[wave][r] = acc[r];
    }
    __syncthreads();
    float sq = 0.0f;
    if (t < R) {
        const float sum = part[0][t] + part[1][t] + part[2][t] + part[3][t];
        const float y = sum * s;
        vout[row0 + t] = y;
        sq = y * y;
    }
    if (wave == 0) {
        for (int off = 32; off > 0; off >>= 1) sq += __shfl_down(sq, off, 64);
        if (lane == 0) atomicAdd(nsq_next, sq);
    }
}

// zero barrier counters + nsq (fresh every call -> no cross-call state)
__global__ void pi_init2_kernel(int* __restrict__ cnt, float* __restrict__ nsq) {
    const int t = threadIdx.x;
    if (t < 64) cnt[t] = 0;
    if (t <= ITERS) nsq[t] = 0.0f;
}

// =========================== persistent kernel ==============================
// 512 blocks x 256 threads, 16 rows/block. iter1: fp32 GEMV(M, ones) fused
// with fp16 conversion; iters 2..50: fp16 gemv; final scale to out.
// Software grid barrier between iterations (51 kernel launches -> 1).
__global__ __launch_bounds__(256, 2) void pi_persist_kernel(
        const float4* __restrict__ M4,
        __half* __restrict__ plane,
        float* __restrict__ vA,
        float* __restrict__ vB,
        float* __restrict__ nsq,
        int* __restrict__ cnt,
        float* __restrict__ out) {
    const int t = threadIdx.x;
    const int row0 = blockIdx.x * RPB;

    // ---- iter 1: v1 = M @ ones (fp32), convert rows to fp16 plane ----
    {
        uint2* hp2 = (uint2*)plane;            // 4 halfs per uint2, row stride 2048
        float acc[RPB];
#pragma unroll
        for (int r = 0; r < RPB; ++r) acc[r] = 0.0f;
        for (int j = 0; j < 8; ++j) {
            const int idx = j * 256 + t;       // float4 index 0..2047
#pragma unroll
            for (int r = 0; r < RPB; ++r) {
                const float4 m = M4[(size_t)(row0 + r) * 2048 + idx];
                acc[r] += m.x + m.y + m.z + m.w;
                uint2 o;
                o.x = pack2h(m.x, m.y);
                o.y = pack2h(m.z, m.w);
                hp2[(size_t)(row0 + r) * 2048 + idx] = o;
            }
        }
        pi_epilogueT<RPB>(acc, t, row0, 1.0f, vB, nsq + 1);
    }
    gbar(cnt, 1);

    // ---- iters 2..50: fp16 gemv ----
    const uint4* h4 = (const uint4*)plane;     // row stride 1024 uint4
    for (int k = 2; k <= ITERS; ++k) {
        const float* vin = (k & 1) ? vA : vB;
        float* vout      = (k & 1) ? vB : vA;
        const float s = rsqrtf(nsq[k - 1]);
        const float4* vin4 = (const float4*)vin;

        float4 va[4], vb[4];
#pragma unroll
        for (int c = 0; c < 4; ++c) {
            va[c] = vin4[2 * (c * 256 + t)];
            vb[c] = vin4[2 * (c * 256 + t) + 1];
        }
        float acc[RPB];
#pragma unroll
        for (int r = 0; r < RPB; ++r) acc[r] = 0.0f;
#pragma unroll
        for (int c = 0; c < 4; ++c) {
            const int idx = c * 256 + t;
#pragma unroll
            for (int r = 0; r < RPB; ++r) {
                const uint4 h = h4[(size_t)(row0 + r) * 1024 + idx];
                const float2 f0 = h2f(h.x);
                const float2 f1 = h2f(h.y);
                const float2 f2 = h2f(h.z);
                const float2 f3 = h2f(h.w);
                acc[r] += f0.x * va[c].x + f0.y * va[c].y + f1.x * va[c].z +
                          f1.y * va[c].w + f2.x * vb[c].x + f2.y * vb[c].y +
                          f3.x * vb[c].z + f3.y * vb[c].w;
            }
        }
        pi_epilogueT<RPB>(acc, t, row0, s, vout, nsq + k);
        gbar(cnt, k);
    }

    // ---- final: out = v50 / ||v50|| (v50 unnormalized in vA) ----
    const float s = rsqrtf(nsq[ITERS]);
    if (t < RPB) out[row0 + t] = vA[row0 + t] * s;
}

// ============================ fallback (round-7) =============================
__global__ void pi_init_kernel(float* __restrict__ bufA, float* __restrict__ nsq) {
    int i = blockIdx.x * blockDim.x + threadIdx.x;
    if (i < N) bufA[i] = 1.0f;
    if (i <= ITERS) nsq[i] = (i == 0) ? 1.0f : 0.0f;
}

__global__ __launch_bounds__(256) void pi_gemv_kernel(
        const float4* __restrict__ M4,
        const float4* __restrict__ vin4,
        float* __restrict__ vout,
        const float* __restrict__ nsq_prev,
        float* __restrict__ nsq_next) {
    const int t = threadIdx.x;
    const int row0 = blockIdx.x * ROWS;
    const float s = rsqrtf(*nsq_prev);
    constexpr int NV = N / 4;
    constexpr int CHUNKS = NV / 256;
    float acc[ROWS];
#pragma unroll
    for (int r = 0; r < ROWS; ++r) acc[r] = 0.0f;
    for (int c = 0; c < CHUNKS; ++c) {
        const int idx = c * 256 + t;
        const float4 vv = vin4[idx];
#pragma unroll
        for (int r = 0; r < ROWS; ++r) {
            const float4 m = M4[(size_t)(row0 + r) * NV + idx];
            acc[r] += m.x * vv.x + m.y * vv.y + m.z * vv.z + m.w * vv.w;
        }
    }
    pi_epilogueT<ROWS>(acc, t, row0, s, vout, nsq_next);
}

__global__ void pi_scale_kernel(const float* __restrict__ vin,
                                const float* __restrict__ nsq,
                                float* __restrict__ out) {
    int i = blockIdx.x * blockDim.x + threadIdx.x;
    const float s = rsqrtf(*nsq);
    if (i < N) out[i] = vin[i] * s;
}

// ================================= launch ====================================
extern "C" void kernel_launch(void* const* d_in, const int* in_sizes, int n_in,
                              void* d_out, int out_size, void* d_ws, size_t ws_size,
                              hipStream_t stream) {
    const float* M = (const float*)d_in[0];
    float* out = (float*)d_out;

    const size_t H_BYTES = (size_t)N * N * 2;   // 128 MiB fp16 plane
    const size_t VEC_BYTES = (size_t)(2 * N + ITERS + 1 + 64) * sizeof(float);
    const bool use2 = (ws_size >= H_BYTES + VEC_BYTES);

    char* ws = (char*)d_ws;
    const float4* M4 = (const float4*)M;

    if (use2) {
        __half* plane = (__half*)ws;
        float* bufA = (float*)(ws + H_BYTES);
        float* bufB = bufA + N;
        float* nsq  = bufB + N;                 // ITERS+1 floats
        int*   cnt  = (int*)(nsq + ITERS + 1);  // 64 ints

        pi_init2_kernel<<<1, 256, 0, stream>>>(cnt, nsq);
        pi_persist_kernel<<<NBLK, 256, 0, stream>>>(
            M4, plane, bufA, bufB, nsq, cnt, out);
        return;
    }

    // fallback: fp32 multi-kernel path
    float* bufA = (float*)ws;
    float* bufB = bufA + N;
    float* nsq  = bufB + N;
    pi_init_kernel<<<(N + 255) / 256, 256, 0, stream>>>(bufA, nsq);
    for (int k = 1; k <= ITERS; ++k) {
        const float* vin = (k & 1) ? bufA : bufB;
        float* vout      = (k & 1) ? bufB : bufA;
        pi_gemv_kernel<<<N / ROWS, 256, 0, stream>>>(
            M4, (const float4*)vin, vout, nsq + (k - 1), nsq + k);
    }
    pi_scale_kernel<<<(N + 255) / 256, 256, 0, stream>>>(bufA, nsq + ITERS, out);
}